// Round 5
// baseline (340.137 us; speedup 1.0000x reference)
//
#include <hip/hip_runtime.h>
#include <hip/hip_bf16.h>

#define BB 64
#define TT 1024
#define AA 128
#define FF 1024
#define DQ 1024
#define DV 512

typedef __bf16 bf16x8_t __attribute__((ext_vector_type(8)));
typedef __bf16 bf16x4_t __attribute__((ext_vector_type(4)));
typedef float f32x4_t __attribute__((ext_vector_type(4)));
typedef _Float16 f16x4_t __attribute__((ext_vector_type(4)));

__device__ __forceinline__ float ftanh(float x) {
    float e = __expf(2.0f * x);
    return 1.0f - 2.0f / (e + 1.0f);
}

__device__ __forceinline__ __bf16 bhi(float x) { return (__bf16)x; }
__device__ __forceinline__ __bf16 blo(float x) {
    __bf16 h = (__bf16)x;
    return (__bf16)(x - (float)h);
}

// ---------------- K_prep: build bf16 hi/lo planes + query GEMM ----------------
// blocks 0..15: wm[a][d] (32 d each); 16..23: wct[f][64] (128 f each);
// 24..55: wlt[a][t] (32 t each); 56..119: query (1 b each)
__global__ __launch_bounds__(256) void k_prep(
    const float* __restrict__ Wm, const float* __restrict__ Wconv,
    const float* __restrict__ Wloc, const float* __restrict__ query,
    const float* __restrict__ Wq,
    __bf16* __restrict__ wmhi, __bf16* __restrict__ wmlo,
    __bf16* __restrict__ wcthi, __bf16* __restrict__ wctlo,
    __bf16* __restrict__ wlthi, __bf16* __restrict__ wltlo,
    float* __restrict__ q_ws) {
    __shared__ float ls[128 * 65];
    int bx = blockIdx.x, tid = threadIdx.x;
    if (bx < 16) {
        // Wm[d][a] -> wm[a][d], 32 d rows
        int d0 = bx * 32;
        for (int i = tid; i < 4096; i += 256) {
            int dd = i >> 7, a = i & 127;
            ls[a * 33 + dd] = Wm[(d0 + dd) * AA + a];
        }
        __syncthreads();
        int a = tid >> 1, half = tid & 1;
#pragma unroll
        for (int g = 0; g < 2; g++) {
            bf16x8_t h8, l8;
#pragma unroll
            for (int j = 0; j < 8; j++) {
                float x = ls[a * 33 + half * 16 + g * 8 + j];
                h8[j] = bhi(x);
                l8[j] = blo(x);
            }
            size_t off = (size_t)a * DV + d0 + half * 16 + g * 8;
            *(bf16x8_t*)(wmhi + off) = h8;
            *(bf16x8_t*)(wmlo + off) = l8;
        }
    } else if (bx < 24) {
        // Wconv[kc][f] -> wct[f][kc], kc padded to 64
        int f0 = (bx - 16) * 128;
        for (int i = tid; i < 8192; i += 256) {
            int kc = i >> 7, f = i & 127;
            ls[f * 65 + kc] = (kc < 62) ? Wconv[kc * FF + f0 + f] : 0.f;
        }
        __syncthreads();
        int f = tid >> 1, half = tid & 1;
#pragma unroll
        for (int g = 0; g < 4; g++) {
            bf16x8_t h8, l8;
#pragma unroll
            for (int j = 0; j < 8; j++) {
                float x = ls[f * 65 + half * 32 + g * 8 + j];
                h8[j] = bhi(x);
                l8[j] = blo(x);
            }
            size_t off = (size_t)(f0 + f) * 64 + half * 32 + g * 8;
            *(bf16x8_t*)(wcthi + off) = h8;
            *(bf16x8_t*)(wctlo + off) = l8;
        }
    } else if (bx < 56) {
        // Wloc[t][a] -> wlt[a][t], 32 t rows
        int t0 = (bx - 24) * 32;
        for (int i = tid; i < 4096; i += 256) {
            int tt = i >> 7, a = i & 127;
            ls[a * 33 + tt] = Wloc[(t0 + tt) * AA + a];
        }
        __syncthreads();
        int a = tid >> 1, half = tid & 1;
#pragma unroll
        for (int g = 0; g < 2; g++) {
            bf16x8_t h8, l8;
#pragma unroll
            for (int j = 0; j < 8; j++) {
                float x = ls[a * 33 + half * 16 + g * 8 + j];
                h8[j] = bhi(x);
                l8[j] = blo(x);
            }
            size_t off = (size_t)a * TT + t0 + half * 16 + g * 8;
            *(bf16x8_t*)(wlthi + off) = h8;
            *(bf16x8_t*)(wltlo + off) = l8;
        }
    } else {
        // query: q[b,a] = tanh(sum_d query[b,d]*Wq[d,a])
        int b = bx - 56;
        int a = tid & 127, half = tid >> 7;
        const float* qrow = query + b * DQ + half * 512;
        float a0 = 0.f, a1 = 0.f, a2 = 0.f, a3 = 0.f;
        for (int d = 0; d < 512; d += 4) {
            float4 qv = *(const float4*)(qrow + d);
            int dg = (half * 512 + d) * AA + a;
            a0 += qv.x * Wq[dg];
            a1 += qv.y * Wq[dg + AA];
            a2 += qv.z * Wq[dg + 2 * AA];
            a3 += qv.w * Wq[dg + 3 * AA];
        }
        ls[tid] = a0 + a1 + a2 + a3;
        __syncthreads();
        if (half == 0) q_ws[b * AA + a] = ftanh(ls[a] + ls[a + 128]);
    }
}

// ---------------- K_zq: z[b][kc][a] = sum_t X[kc][t]*Wloc[t][a] via MFMA ----------------
// X[kc=2k+c][t] = x[b, t+k-15, c]. One block per b. Output transposed bf16 hi/lo [b][a][64].
__global__ __launch_bounds__(256) void k_zq(
    const float* __restrict__ xcat,
    const __bf16* __restrict__ wlthi, const __bf16* __restrict__ wltlo,
    __bf16* __restrict__ zthi, __bf16* __restrict__ ztlo) {
    int b = blockIdx.x, tid = threadIdx.x;
    __shared__ float xs0[1056], xs1[1056];
    __shared__ float zs[64 * 132];
    for (int i = tid; i < 1056; i += 256) {
        int t = i - 16;
        float2 xv = (t >= 0 && t < TT) ? *(const float2*)(xcat + (size_t)(b * TT + t) * 2)
                                       : make_float2(0.f, 0.f);
        xs0[i] = xv.x;
        xs1[i] = xv.y;
    }
    __syncthreads();
    int lane = tid & 63, wid = tid >> 6;
    int wm = wid >> 1, wn = wid & 1;
    int l15 = lane & 15, lq = lane >> 4;

    f32x4_t zacc[2][4];
#pragma unroll
    for (int mi = 0; mi < 2; mi++)
#pragma unroll
        for (int ni = 0; ni < 4; ni++) zacc[mi][ni] = (f32x4_t){0.f, 0.f, 0.f, 0.f};

    for (int t0 = 0; t0 < TT; t0 += 32) {
        bf16x8_t ah[2], al[2];
#pragma unroll
        for (int mi = 0; mi < 2; mi++) {
            int kc = wm * 32 + mi * 16 + l15;
            const float* xsc = (kc & 1) ? xs1 : xs0;
            int base = t0 + lq * 8 + (kc >> 1) + 1;
#pragma unroll
            for (int j = 0; j < 8; j++) {
                float x = xsc[base + j];
                ah[mi][j] = bhi(x);
                al[mi][j] = blo(x);
            }
        }
#pragma unroll
        for (int ni = 0; ni < 4; ni++) {
            int a = wn * 64 + ni * 16 + l15;
            size_t off = (size_t)a * TT + t0 + lq * 8;
            bf16x8_t bh = *(const bf16x8_t*)(wlthi + off);
            bf16x8_t bl = *(const bf16x8_t*)(wltlo + off);
#pragma unroll
            for (int mi = 0; mi < 2; mi++) {
                zacc[mi][ni] = __builtin_amdgcn_mfma_f32_16x16x32_bf16(ah[mi], bh, zacc[mi][ni], 0, 0, 0);
                zacc[mi][ni] = __builtin_amdgcn_mfma_f32_16x16x32_bf16(al[mi], bh, zacc[mi][ni], 0, 0, 0);
                zacc[mi][ni] = __builtin_amdgcn_mfma_f32_16x16x32_bf16(ah[mi], bl, zacc[mi][ni], 0, 0, 0);
            }
        }
    }
    // C[kc][a] -> LDS -> transposed bf16 hi/lo [a][kc]
#pragma unroll
    for (int mi = 0; mi < 2; mi++)
#pragma unroll
        for (int ni = 0; ni < 4; ni++)
#pragma unroll
            for (int r = 0; r < 4; r++)
                zs[(wm * 32 + mi * 16 + lq * 4 + r) * 132 + wn * 64 + ni * 16 + l15] = zacc[mi][ni][r];
    __syncthreads();
    int a = tid >> 1, half = tid & 1;
#pragma unroll
    for (int g = 0; g < 4; g++) {
        bf16x8_t h8, l8;
#pragma unroll
        for (int j = 0; j < 8; j++) {
            float x = zs[(half * 32 + g * 8 + j) * 132 + a];
            h8[j] = bhi(x);
            l8[j] = blo(x);
        }
        size_t off = ((size_t)b * AA + a) * 64 + half * 32 + g * 8;
        *(bf16x8_t*)(zthi + off) = h8;
        *(bf16x8_t*)(ztlo + off) = l8;
    }
}

// ---------------- K_main: v = tanh(value@Wm), loc = tanh(wct@z), fused score ----------------
// 64 t-rows x 128 a per block; 1024 blocks; 4 waves (2x2), each 32x64.
__global__ __launch_bounds__(256, 4) void k_main(
    const float* __restrict__ value,
    const __bf16* __restrict__ wmhi, const __bf16* __restrict__ wmlo,
    const __bf16* __restrict__ wcthi, const __bf16* __restrict__ wctlo,
    const __bf16* __restrict__ zthi, const __bf16* __restrict__ ztlo,
    const float* __restrict__ q_ws, const float* __restrict__ Wv,
    float* __restrict__ v_ws, float* __restrict__ score) {
    int b = blockIdx.x >> 4;
    int trow0 = (blockIdx.x & 15) << 6;
    int tid = threadIdx.x;
    int lane = tid & 63, wid = tid >> 6;
    int wm = wid >> 1, wn = wid & 1;
    int l15 = lane & 15, lq = lane >> 4;

    __shared__ __bf16 as_hi[64 * 40];
    __shared__ __bf16 as_lo[64 * 40];
    __shared__ float sc_red[128];

    // ---- loc gemm first (K=64), compress to packed f16 tanh(loc) ----
    f16x4_t lt[2][4];
    {
        f32x4_t lacc[2][4];
#pragma unroll
        for (int mi = 0; mi < 2; mi++)
#pragma unroll
            for (int ni = 0; ni < 4; ni++) lacc[mi][ni] = (f32x4_t){0.f, 0.f, 0.f, 0.f};
#pragma unroll
        for (int kc0 = 0; kc0 < 64; kc0 += 32) {
            bf16x8_t a2h[2], a2l[2];
#pragma unroll
            for (int mi = 0; mi < 2; mi++) {
                int f = trow0 + wm * 32 + mi * 16 + l15;
                a2h[mi] = *(const bf16x8_t*)(wcthi + (size_t)f * 64 + kc0 + lq * 8);
                a2l[mi] = *(const bf16x8_t*)(wctlo + (size_t)f * 64 + kc0 + lq * 8);
            }
#pragma unroll
            for (int ni = 0; ni < 4; ni++) {
                int a = wn * 64 + ni * 16 + l15;
                size_t off = ((size_t)b * AA + a) * 64 + kc0 + lq * 8;
                bf16x8_t bh = *(const bf16x8_t*)(zthi + off);
                bf16x8_t bl = *(const bf16x8_t*)(ztlo + off);
#pragma unroll
                for (int mi = 0; mi < 2; mi++) {
                    lacc[mi][ni] = __builtin_amdgcn_mfma_f32_16x16x32_bf16(a2h[mi], bh, lacc[mi][ni], 0, 0, 0);
                    lacc[mi][ni] = __builtin_amdgcn_mfma_f32_16x16x32_bf16(a2l[mi], bh, lacc[mi][ni], 0, 0, 0);
                    lacc[mi][ni] = __builtin_amdgcn_mfma_f32_16x16x32_bf16(a2h[mi], bl, lacc[mi][ni], 0, 0, 0);
                }
            }
        }
#pragma unroll
        for (int mi = 0; mi < 2; mi++)
#pragma unroll
            for (int ni = 0; ni < 4; ni++)
#pragma unroll
                for (int r = 0; r < 4; r++) lt[mi][ni][r] = (_Float16)ftanh(lacc[mi][ni][r]);
    }

    // ---- main K loop: v_pre = value @ Wm (3-term bf16 split) ----
    f32x4_t acc[2][4];
#pragma unroll
    for (int mi = 0; mi < 2; mi++)
#pragma unroll
        for (int ni = 0; ni < 4; ni++) acc[mi][ni] = (f32x4_t){0.f, 0.f, 0.f, 0.f};

    const float* vbase = value + (size_t)(b * TT + trow0) * DV;
    float4 cur[2];
#pragma unroll
    for (int l = 0; l < 2; l++) {
        int slot = tid + l * 256;
        cur[l] = *(const float4*)(vbase + (size_t)(slot >> 3) * DV + (slot & 7) * 4);
    }
    for (int it = 0; it < 16; ++it) {
        int d0 = it * 32;
        __syncthreads();
#pragma unroll
        for (int l = 0; l < 2; l++) {
            int slot = tid + l * 256;
            int t = slot >> 3, c4 = slot & 7;
            float4 v4 = cur[l];
            bf16x4_t hv, lv;
            hv[0] = bhi(v4.x); lv[0] = blo(v4.x);
            hv[1] = bhi(v4.y); lv[1] = blo(v4.y);
            hv[2] = bhi(v4.z); lv[2] = blo(v4.z);
            hv[3] = bhi(v4.w); lv[3] = blo(v4.w);
            *(bf16x4_t*)(as_hi + t * 40 + c4 * 4) = hv;
            *(bf16x4_t*)(as_lo + t * 40 + c4 * 4) = lv;
        }
        __syncthreads();
        if (it < 15) {
#pragma unroll
            for (int l = 0; l < 2; l++) {
                int slot = tid + l * 256;
                cur[l] = *(const float4*)(vbase + (size_t)(slot >> 3) * DV + d0 + 32 + (slot & 7) * 4);
            }
        }
        bf16x8_t ah[2], al[2];
#pragma unroll
        for (int mi = 0; mi < 2; mi++) {
            int off2 = (wm * 32 + mi * 16 + l15) * 40 + lq * 8;
            ah[mi] = *(const bf16x8_t*)(as_hi + off2);
            al[mi] = *(const bf16x8_t*)(as_lo + off2);
        }
#pragma unroll
        for (int ni = 0; ni < 4; ni++) {
            int a = wn * 64 + ni * 16 + l15;
            size_t off = (size_t)a * DV + d0 + lq * 8;
            bf16x8_t bh = *(const bf16x8_t*)(wmhi + off);
            bf16x8_t bl = *(const bf16x8_t*)(wmlo + off);
#pragma unroll
            for (int mi = 0; mi < 2; mi++) {
                acc[mi][ni] = __builtin_amdgcn_mfma_f32_16x16x32_bf16(ah[mi], bh, acc[mi][ni], 0, 0, 0);
                acc[mi][ni] = __builtin_amdgcn_mfma_f32_16x16x32_bf16(al[mi], bh, acc[mi][ni], 0, 0, 0);
                acc[mi][ni] = __builtin_amdgcn_mfma_f32_16x16x32_bf16(ah[mi], bl, acc[mi][ni], 0, 0, 0);
            }
        }
    }

    // ---- epilogue ----
    float qv[4], wv[4];
#pragma unroll
    for (int ni = 0; ni < 4; ni++) {
        int a = wn * 64 + ni * 16 + l15;
        qv[ni] = q_ws[b * AA + a];
        wv[ni] = Wv[a];
    }
#pragma unroll
    for (int mi = 0; mi < 2; mi++) {
#pragma unroll
        for (int r = 0; r < 4; r++) {
            int tl = wm * 32 + mi * 16 + lq * 4 + r;
            int t = trow0 + tl;
            float s = 0.f;
#pragma unroll
            for (int ni = 0; ni < 4; ni++) {
                float v = ftanh(acc[mi][ni][r]);
                int a = wn * 64 + ni * 16 + l15;
                v_ws[(size_t)(b * TT + t) * AA + a] = v;
                s += ftanh(qv[ni] + v + (float)lt[mi][ni][r]) * wv[ni];
            }
            s += __shfl_xor(s, 1, 64);
            s += __shfl_xor(s, 2, 64);
            s += __shfl_xor(s, 4, 64);
            s += __shfl_xor(s, 8, 64);
            if (l15 == 0) sc_red[wn * 64 + tl] = s;
        }
    }
    __syncthreads();
    if (tid < 64) score[b * TT + trow0 + tid] = sc_red[tid] + sc_red[64 + tid];
}

// ---------------- K_softmax ----------------
__global__ void k_softmax(const float* __restrict__ score, float* __restrict__ out_align) {
    int b = blockIdx.x, tid = threadIdx.x;
    __shared__ float red[4];
    float s[4];
#pragma unroll
    for (int i = 0; i < 4; i++) s[i] = score[b * TT + tid + i * 256];
    float m = fmaxf(fmaxf(s[0], s[1]), fmaxf(s[2], s[3]));
    for (int off = 32; off; off >>= 1) m = fmaxf(m, __shfl_xor(m, off, 64));
    int wid = tid >> 6;
    if ((tid & 63) == 0) red[wid] = m;
    __syncthreads();
    float M = fmaxf(fmaxf(red[0], red[1]), fmaxf(red[2], red[3]));
    __syncthreads();
    float e[4];
    float sum = 0.f;
#pragma unroll
    for (int i = 0; i < 4; i++) { e[i] = __expf(s[i] - M); sum += e[i]; }
    for (int off = 32; off; off >>= 1) sum += __shfl_xor(sum, off, 64);
    if ((tid & 63) == 0) red[wid] = sum;
    __syncthreads();
    float inv = 1.0f / (red[0] + red[1] + red[2] + red[3]);
#pragma unroll
    for (int i = 0; i < 4; i++) out_align[b * TT + tid + i * 256] = e[i] * inv;
}

// ---------------- K_context: context[b,a] = sum_t align[b,t] * v[b,t,a] ----------------
__global__ void k_context(const float* __restrict__ align, const float* __restrict__ v_ws,
                          float* __restrict__ out_ctx) {
    int b = blockIdx.y, t0 = blockIdx.x * 64, tid = threadIdx.x;
    int a0 = (tid & 31) * 4, tl = tid >> 5;
    __shared__ float sh[8 * 132];
    f32x4_t acc = (f32x4_t){0.f, 0.f, 0.f, 0.f};
    for (int tt = tl; tt < 64; tt += 8) {
        float w = align[b * TT + t0 + tt];
        f32x4_t vv = *(const f32x4_t*)(v_ws + (size_t)(b * TT + t0 + tt) * AA + a0);
        acc += w * vv;
    }
    *(f32x4_t*)&sh[tl * 132 + a0] = acc;
    __syncthreads();
    if (tid < 128) {
        float s = 0.f;
#pragma unroll
        for (int j = 0; j < 8; j++) s += sh[j * 132 + tid];
        atomicAdd(out_ctx + b * AA + tid, s);
    }
}

extern "C" void kernel_launch(void* const* d_in, const int* in_sizes, int n_in,
                              void* d_out, int out_size, void* d_ws, size_t ws_size,
                              hipStream_t stream) {
    const float* query = (const float*)d_in[0];
    const float* value = (const float*)d_in[1];
    const float* xcat  = (const float*)d_in[2];
    const float* Wq    = (const float*)d_in[3];
    const float* Wm    = (const float*)d_in[4];
    const float* Wv    = (const float*)d_in[5];
    const float* Wconv = (const float*)d_in[6];
    const float* Wloc  = (const float*)d_in[7];
    float* out = (float*)d_out;

    float* ws = (float*)d_ws;
    float* q_ws  = ws;                   // 8192
    float* sc_ws = q_ws + 8192;          // 65536
    float* v_ws  = sc_ws + 65536;        // 8388608
    __bf16* wmhi  = (__bf16*)(v_ws + 8388608);
    __bf16* wmlo  = wmhi + 65536;
    __bf16* wcthi = wmlo + 65536;
    __bf16* wctlo = wcthi + 65536;
    __bf16* wlthi = wctlo + 65536;       // 131072
    __bf16* wltlo = wlthi + 131072;
    __bf16* zthi  = wltlo + 131072;      // 524288
    __bf16* ztlo  = zthi + 524288;

    (void)hipMemsetAsync(out, 0, (size_t)8192 * 4, stream);  // context accumulated via atomics

    k_prep<<<120, 256, 0, stream>>>(Wm, Wconv, Wloc, query, Wq,
                                    wmhi, wmlo, wcthi, wctlo, wlthi, wltlo, q_ws);
    k_zq<<<BB, 256, 0, stream>>>(xcat, wlthi, wltlo, zthi, ztlo);
    k_main<<<1024, 256, 0, stream>>>(value, wmhi, wmlo, wcthi, wctlo, zthi, ztlo,
                                     q_ws, Wv, v_ws, sc_ws);
    k_softmax<<<BB, 256, 0, stream>>>(sc_ws, out + 8192);
    k_context<<<dim3(16, BB), 256, 0, stream>>>(out + 8192, v_ws, out);
}

// Round 6
// 294.490 us; speedup vs baseline: 1.1550x; 1.1550x over previous
//
#include <hip/hip_runtime.h>
#include <hip/hip_bf16.h>

#define BB 64
#define TT 1024
#define AA 128
#define FF 1024
#define DQ 1024
#define DV 512

typedef __bf16 bf16x8_t __attribute__((ext_vector_type(8)));
typedef __bf16 bf16x4_t __attribute__((ext_vector_type(4)));
typedef float f32x4_t __attribute__((ext_vector_type(4)));
typedef _Float16 f16x4_t __attribute__((ext_vector_type(4)));

__device__ __forceinline__ float ftanh(float x) {
    float e = __expf(2.0f * x);
    return 1.0f - 2.0f / (e + 1.0f);
}

__device__ __forceinline__ __bf16 bhi(float x) { return (__bf16)x; }
__device__ __forceinline__ __bf16 blo(float x) {
    __bf16 h = (__bf16)x;
    return (__bf16)(x - (float)h);
}

// ---------------- K_prep ----------------
// blocks 0..15:  Wm slab s (32 d) -> packed pwm hi/lo, fragment order
//                P[((s*8+g)*64 + lane)*8 + j] = Wm[s*32 + (lane>>4)*8 + j][g*16 + (lane&15)]
// blocks 16..23: Wconv -> wct[f][64] hi/lo (kc padded to 64)
// blocks 24..55: Wloc slab s2 (32 t) -> packed pwl hi/lo, same fragment order over t
// blocks 56..119: query GEMM (1 b each)
__global__ __launch_bounds__(256) void k_prep(
    const float* __restrict__ Wm, const float* __restrict__ Wconv,
    const float* __restrict__ Wloc, const float* __restrict__ query,
    const float* __restrict__ Wq,
    __bf16* __restrict__ pwmhi, __bf16* __restrict__ pwmlo,
    __bf16* __restrict__ wcthi, __bf16* __restrict__ wctlo,
    __bf16* __restrict__ pwlhi, __bf16* __restrict__ pwllo,
    float* __restrict__ q_ws) {
    __shared__ float ls[128 * 65];
    int bx = blockIdx.x, tid = threadIdx.x;
    if (bx < 16) {
        int s = bx, d0 = s * 32;
        for (int i = tid; i < 4096; i += 256) {
            int dd = i >> 7, a = i & 127;
            ls[a * 33 + dd] = Wm[(d0 + dd) * AA + a];
        }
        __syncthreads();
#pragma unroll
        for (int u = 0; u < 2; u++) {
            int pos = tid * 2 + u;                 // 0..511
            int l15 = pos & 15, lq = (pos >> 4) & 3, g = pos >> 6;
            bf16x8_t h8, l8;
#pragma unroll
            for (int j = 0; j < 8; j++) {
                float x = ls[(g * 16 + l15) * 33 + lq * 8 + j];
                h8[j] = bhi(x);
                l8[j] = blo(x);
            }
            size_t off = (size_t)(s * 512 + pos) * 8;
            *(bf16x8_t*)(pwmhi + off) = h8;
            *(bf16x8_t*)(pwmlo + off) = l8;
        }
    } else if (bx < 24) {
        int f0 = (bx - 16) * 128;
        for (int i = tid; i < 8192; i += 256) {
            int kc = i >> 7, f = i & 127;
            ls[f * 65 + kc] = (kc < 62) ? Wconv[kc * FF + f0 + f] : 0.f;
        }
        __syncthreads();
        int f = tid >> 1, half = tid & 1;
#pragma unroll
        for (int g = 0; g < 4; g++) {
            bf16x8_t h8, l8;
#pragma unroll
            for (int j = 0; j < 8; j++) {
                float x = ls[f * 65 + half * 32 + g * 8 + j];
                h8[j] = bhi(x);
                l8[j] = blo(x);
            }
            size_t off = (size_t)(f0 + f) * 64 + half * 32 + g * 8;
            *(bf16x8_t*)(wcthi + off) = h8;
            *(bf16x8_t*)(wctlo + off) = l8;
        }
    } else if (bx < 56) {
        int s2 = bx - 24, t0 = s2 * 32;
        for (int i = tid; i < 4096; i += 256) {
            int tt = i >> 7, a = i & 127;
            ls[a * 33 + tt] = Wloc[(t0 + tt) * AA + a];
        }
        __syncthreads();
#pragma unroll
        for (int u = 0; u < 2; u++) {
            int pos = tid * 2 + u;
            int l15 = pos & 15, lq = (pos >> 4) & 3, g = pos >> 6;
            bf16x8_t h8, l8;
#pragma unroll
            for (int j = 0; j < 8; j++) {
                float x = ls[(g * 16 + l15) * 33 + lq * 8 + j];
                h8[j] = bhi(x);
                l8[j] = blo(x);
            }
            size_t off = (size_t)(s2 * 512 + pos) * 8;
            *(bf16x8_t*)(pwlhi + off) = h8;
            *(bf16x8_t*)(pwllo + off) = l8;
        }
    } else {
        int b = bx - 56;
        int a = tid & 127, half = tid >> 7;
        const float* qrow = query + b * DQ + half * 512;
        float a0 = 0.f, a1 = 0.f, a2 = 0.f, a3 = 0.f;
        for (int d = 0; d < 512; d += 4) {
            float4 qv = *(const float4*)(qrow + d);
            int dg = (half * 512 + d) * AA + a;
            a0 += qv.x * Wq[dg];
            a1 += qv.y * Wq[dg + AA];
            a2 += qv.z * Wq[dg + 2 * AA];
            a3 += qv.w * Wq[dg + 3 * AA];
        }
        ls[tid] = a0 + a1 + a2 + a3;
        __syncthreads();
        if (half == 0) q_ws[b * AA + a] = ftanh(ls[a] + ls[a + 128]);
    }
}

// ---------------- K_zq: z[b][kc][a] = sum_t X[kc][t]*Wloc[t][a] via MFMA ----------------
// B frags from packed pwl (coalesced). Output transposed bf16 hi/lo [b][a][64].
__global__ __launch_bounds__(256) void k_zq(
    const float* __restrict__ xcat,
    const __bf16* __restrict__ pwlhi, const __bf16* __restrict__ pwllo,
    __bf16* __restrict__ zthi, __bf16* __restrict__ ztlo) {
    int b = blockIdx.x, tid = threadIdx.x;
    __shared__ float xs0[1056], xs1[1056];
    __shared__ float zs[64 * 132];
    for (int i = tid; i < 1056; i += 256) {
        int t = i - 16;
        float2 xv = (t >= 0 && t < TT) ? *(const float2*)(xcat + (size_t)(b * TT + t) * 2)
                                       : make_float2(0.f, 0.f);
        xs0[i] = xv.x;
        xs1[i] = xv.y;
    }
    __syncthreads();
    int lane = tid & 63, wid = tid >> 6;
    int wm = wid >> 1, wn = wid & 1;
    int l15 = lane & 15, lq = lane >> 4;

    f32x4_t zacc[2][4];
#pragma unroll
    for (int mi = 0; mi < 2; mi++)
#pragma unroll
        for (int ni = 0; ni < 4; ni++) zacc[mi][ni] = (f32x4_t){0.f, 0.f, 0.f, 0.f};

    for (int s = 0; s < 32; s++) {
        int t0 = s * 32;
        bf16x8_t bh[4], bl[4];
#pragma unroll
        for (int ni = 0; ni < 4; ni++) {
            size_t poff = (size_t)((s * 8 + wn * 4 + ni) * 64 + lane) * 8;
            bh[ni] = *(const bf16x8_t*)(pwlhi + poff);
            bl[ni] = *(const bf16x8_t*)(pwllo + poff);
        }
        bf16x8_t ah[2], al[2];
#pragma unroll
        for (int mi = 0; mi < 2; mi++) {
            int kc = wm * 32 + mi * 16 + l15;
            const float* xsc = (kc & 1) ? xs1 : xs0;
            int base = t0 + lq * 8 + (kc >> 1) + 1;
#pragma unroll
            for (int j = 0; j < 8; j++) {
                float x = xsc[base + j];
                ah[mi][j] = bhi(x);
                al[mi][j] = blo(x);
            }
        }
#pragma unroll
        for (int ni = 0; ni < 4; ni++)
#pragma unroll
            for (int mi = 0; mi < 2; mi++) {
                zacc[mi][ni] = __builtin_amdgcn_mfma_f32_16x16x32_bf16(ah[mi], bh[ni], zacc[mi][ni], 0, 0, 0);
                zacc[mi][ni] = __builtin_amdgcn_mfma_f32_16x16x32_bf16(al[mi], bh[ni], zacc[mi][ni], 0, 0, 0);
                zacc[mi][ni] = __builtin_amdgcn_mfma_f32_16x16x32_bf16(ah[mi], bl[ni], zacc[mi][ni], 0, 0, 0);
            }
    }
#pragma unroll
    for (int mi = 0; mi < 2; mi++)
#pragma unroll
        for (int ni = 0; ni < 4; ni++)
#pragma unroll
            for (int r = 0; r < 4; r++)
                zs[(wm * 32 + mi * 16 + lq * 4 + r) * 132 + wn * 64 + ni * 16 + l15] = zacc[mi][ni][r];
    __syncthreads();
    int a = tid >> 1, half = tid & 1;
#pragma unroll
    for (int g = 0; g < 4; g++) {
        bf16x8_t h8, l8;
#pragma unroll
        for (int j = 0; j < 8; j++) {
            float x = zs[(half * 32 + g * 8 + j) * 132 + a];
            h8[j] = bhi(x);
            l8[j] = blo(x);
        }
        size_t off = ((size_t)b * AA + a) * 64 + half * 32 + g * 8;
        *(bf16x8_t*)(zthi + off) = h8;
        *(bf16x8_t*)(ztlo + off) = l8;
    }
}

// ---------------- K_main: v = tanh(value@Wm), loc = tanh(wct@z), fused score ----------------
// 128 t-rows x 128 a per block; 512 blocks; 4 waves (2x2), each 64x64.
// B frags from packed pwm (coalesced global, L2-hot); A staged via LDS.
__global__ __launch_bounds__(256) void k_main(
    const float* __restrict__ value,
    const __bf16* __restrict__ pwmhi, const __bf16* __restrict__ pwmlo,
    const __bf16* __restrict__ wcthi, const __bf16* __restrict__ wctlo,
    const __bf16* __restrict__ zthi, const __bf16* __restrict__ ztlo,
    const float* __restrict__ q_ws, const float* __restrict__ Wv,
    _Float16* __restrict__ v_ws, float* __restrict__ score) {
    int b = blockIdx.x >> 3;
    int trow0 = (blockIdx.x & 7) << 7;
    int tid = threadIdx.x;
    int lane = tid & 63, wid = tid >> 6;
    int wm = wid >> 1, wn = wid & 1;
    int l15 = lane & 15, lq = lane >> 4;

    __shared__ __bf16 as_hi[128 * 40];
    __shared__ __bf16 as_lo[128 * 40];
    __shared__ float sc_red[256];

    f32x4_t acc[4][4];
#pragma unroll
    for (int mi = 0; mi < 4; mi++)
#pragma unroll
        for (int ni = 0; ni < 4; ni++) acc[mi][ni] = (f32x4_t){0.f, 0.f, 0.f, 0.f};

    const float* vbase = value + (size_t)(b * TT + trow0) * DV;
    int t0r = tid >> 3, c4 = tid & 7;
    float4 cur[4];
#pragma unroll
    for (int l = 0; l < 4; l++)
        cur[l] = *(const float4*)(vbase + (size_t)(t0r + 32 * l) * DV + c4 * 4);

    for (int it = 0; it < 16; ++it) {
        int d0 = it * 32;
        // B frag loads: coalesced packed, issued before barrier so they fly during drain
        bf16x8_t bh[4], bl[4];
#pragma unroll
        for (int ni = 0; ni < 4; ni++) {
            size_t poff = (size_t)((it * 8 + wn * 4 + ni) * 64 + lane) * 8;
            bh[ni] = *(const bf16x8_t*)(pwmhi + poff);
            bl[ni] = *(const bf16x8_t*)(pwmlo + poff);
        }
        __syncthreads();  // prev iter's LDS reads complete before overwrite
#pragma unroll
        for (int l = 0; l < 4; l++) {
            int t = t0r + 32 * l;
            float4 v4 = cur[l];
            bf16x4_t hv, lv;
            hv[0] = bhi(v4.x); lv[0] = blo(v4.x);
            hv[1] = bhi(v4.y); lv[1] = blo(v4.y);
            hv[2] = bhi(v4.z); lv[2] = blo(v4.z);
            hv[3] = bhi(v4.w); lv[3] = blo(v4.w);
            *(bf16x4_t*)(as_hi + t * 40 + c4 * 4) = hv;
            *(bf16x4_t*)(as_lo + t * 40 + c4 * 4) = lv;
        }
        __syncthreads();
        if (it < 15) {
#pragma unroll
            for (int l = 0; l < 4; l++)
                cur[l] = *(const float4*)(vbase + (size_t)(t0r + 32 * l) * DV + d0 + 32 + c4 * 4);
        }
        bf16x8_t ah[4], al[4];
#pragma unroll
        for (int mi = 0; mi < 4; mi++) {
            int off2 = (wm * 64 + mi * 16 + l15) * 40 + lq * 8;
            ah[mi] = *(const bf16x8_t*)(as_hi + off2);
            al[mi] = *(const bf16x8_t*)(as_lo + off2);
        }
#pragma unroll
        for (int mi = 0; mi < 4; mi++)
#pragma unroll
            for (int ni = 0; ni < 4; ni++) {
                acc[mi][ni] = __builtin_amdgcn_mfma_f32_16x16x32_bf16(ah[mi], bh[ni], acc[mi][ni], 0, 0, 0);
                acc[mi][ni] = __builtin_amdgcn_mfma_f32_16x16x32_bf16(al[mi], bh[ni], acc[mi][ni], 0, 0, 0);
                acc[mi][ni] = __builtin_amdgcn_mfma_f32_16x16x32_bf16(ah[mi], bl[ni], acc[mi][ni], 0, 0, 0);
            }
    }

    // ---- loc gemm (after main loop; frees regs during it): K=64, kc 62/63 zero in wct ----
    f32x4_t lacc[4][4];
#pragma unroll
    for (int mi = 0; mi < 4; mi++)
#pragma unroll
        for (int ni = 0; ni < 4; ni++) lacc[mi][ni] = (f32x4_t){0.f, 0.f, 0.f, 0.f};
#pragma unroll
    for (int kc0 = 0; kc0 < 64; kc0 += 32) {
        bf16x8_t a2h[4], a2l[4], b2h[4], b2l[4];
#pragma unroll
        for (int mi = 0; mi < 4; mi++) {
            int f = trow0 + wm * 64 + mi * 16 + l15;
            a2h[mi] = *(const bf16x8_t*)(wcthi + (size_t)f * 64 + kc0 + lq * 8);
            a2l[mi] = *(const bf16x8_t*)(wctlo + (size_t)f * 64 + kc0 + lq * 8);
        }
#pragma unroll
        for (int ni = 0; ni < 4; ni++) {
            int a = wn * 64 + ni * 16 + l15;
            size_t off = ((size_t)b * AA + a) * 64 + kc0 + lq * 8;
            b2h[ni] = *(const bf16x8_t*)(zthi + off);
            b2l[ni] = *(const bf16x8_t*)(ztlo + off);
        }
#pragma unroll
        for (int mi = 0; mi < 4; mi++)
#pragma unroll
            for (int ni = 0; ni < 4; ni++) {
                lacc[mi][ni] = __builtin_amdgcn_mfma_f32_16x16x32_bf16(a2h[mi], b2h[ni], lacc[mi][ni], 0, 0, 0);
                lacc[mi][ni] = __builtin_amdgcn_mfma_f32_16x16x32_bf16(a2l[mi], b2h[ni], lacc[mi][ni], 0, 0, 0);
                lacc[mi][ni] = __builtin_amdgcn_mfma_f32_16x16x32_bf16(a2h[mi], b2l[ni], lacc[mi][ni], 0, 0, 0);
            }
    }

    // ---- epilogue ----
    float qv[4], wv[4];
#pragma unroll
    for (int ni = 0; ni < 4; ni++) {
        int a = wn * 64 + ni * 16 + l15;
        qv[ni] = q_ws[b * AA + a];
        wv[ni] = Wv[a];
    }
#pragma unroll
    for (int mi = 0; mi < 4; mi++) {
#pragma unroll
        for (int r = 0; r < 4; r++) {
            int tl = wm * 64 + mi * 16 + lq * 4 + r;
            int t = trow0 + tl;
            float s = 0.f;
#pragma unroll
            for (int ni = 0; ni < 4; ni++) {
                float v = ftanh(acc[mi][ni][r]);
                float loc = ftanh(lacc[mi][ni][r]);
                int a = wn * 64 + ni * 16 + l15;
                v_ws[(size_t)(b * TT + t) * AA + a] = (_Float16)v;
                s += ftanh(qv[ni] + v + loc) * wv[ni];
            }
            s += __shfl_xor(s, 1, 64);
            s += __shfl_xor(s, 2, 64);
            s += __shfl_xor(s, 4, 64);
            s += __shfl_xor(s, 8, 64);
            if (l15 == 0) sc_red[wn * 128 + tl] = s;
        }
    }
    __syncthreads();
    if (tid < 128) score[b * TT + trow0 + tid] = sc_red[tid] + sc_red[128 + tid];
}

// ---------------- K_softmax ----------------
__global__ void k_softmax(const float* __restrict__ score, float* __restrict__ out_align) {
    int b = blockIdx.x, tid = threadIdx.x;
    __shared__ float red[4];
    float s[4];
#pragma unroll
    for (int i = 0; i < 4; i++) s[i] = score[b * TT + tid + i * 256];
    float m = fmaxf(fmaxf(s[0], s[1]), fmaxf(s[2], s[3]));
    for (int off = 32; off; off >>= 1) m = fmaxf(m, __shfl_xor(m, off, 64));
    int wid = tid >> 6;
    if ((tid & 63) == 0) red[wid] = m;
    __syncthreads();
    float M = fmaxf(fmaxf(red[0], red[1]), fmaxf(red[2], red[3]));
    __syncthreads();
    float e[4];
    float sum = 0.f;
#pragma unroll
    for (int i = 0; i < 4; i++) { e[i] = __expf(s[i] - M); sum += e[i]; }
    for (int off = 32; off; off >>= 1) sum += __shfl_xor(sum, off, 64);
    if ((tid & 63) == 0) red[wid] = sum;
    __syncthreads();
    float inv = 1.0f / (red[0] + red[1] + red[2] + red[3]);
#pragma unroll
    for (int i = 0; i < 4; i++) out_align[b * TT + tid + i * 256] = e[i] * inv;
}

// ---------------- K_context: context[b,a] = sum_t align[b,t] * v[b,t,a] (v in f16) ----------------
__global__ void k_context(const float* __restrict__ align, const _Float16* __restrict__ v_ws,
                          float* __restrict__ out_ctx) {
    int b = blockIdx.y, t0 = blockIdx.x * 64, tid = threadIdx.x;
    int a0 = (tid & 31) * 4, tl = tid >> 5;
    __shared__ float sh[8 * 132];
    f32x4_t acc = (f32x4_t){0.f, 0.f, 0.f, 0.f};
    for (int tt = tl; tt < 64; tt += 8) {
        float w = align[b * TT + t0 + tt];
        f16x4_t vv = *(const f16x4_t*)(v_ws + (size_t)(b * TT + t0 + tt) * AA + a0);
        acc[0] += w * (float)vv[0];
        acc[1] += w * (float)vv[1];
        acc[2] += w * (float)vv[2];
        acc[3] += w * (float)vv[3];
    }
    *(f32x4_t*)&sh[tl * 132 + a0] = acc;
    __syncthreads();
    if (tid < 128) {
        float s = 0.f;
#pragma unroll
        for (int j = 0; j < 8; j++) s += sh[j * 132 + tid];
        atomicAdd(out_ctx + b * AA + tid, s);
    }
}

extern "C" void kernel_launch(void* const* d_in, const int* in_sizes, int n_in,
                              void* d_out, int out_size, void* d_ws, size_t ws_size,
                              hipStream_t stream) {
    const float* query = (const float*)d_in[0];
    const float* value = (const float*)d_in[1];
    const float* xcat  = (const float*)d_in[2];
    const float* Wq    = (const float*)d_in[3];
    const float* Wm    = (const float*)d_in[4];
    const float* Wv    = (const float*)d_in[5];
    const float* Wconv = (const float*)d_in[6];
    const float* Wloc  = (const float*)d_in[7];
    float* out = (float*)d_out;

    float* ws = (float*)d_ws;
    float* q_ws  = ws;                       // 8192
    float* sc_ws = q_ws + 8192;              // 65536
    _Float16* v_ws = (_Float16*)(sc_ws + 65536);  // 8388608 halfs = 4194304 floats
    __bf16* pwmhi = (__bf16*)(sc_ws + 65536 + 4194304);
    __bf16* pwmlo = pwmhi + 65536;
    __bf16* wcthi = pwmlo + 65536;
    __bf16* wctlo = wcthi + 65536;
    __bf16* pwlhi = wctlo + 65536;           // 131072
    __bf16* pwllo = pwlhi + 131072;
    __bf16* zthi  = pwllo + 131072;          // 524288
    __bf16* ztlo  = zthi + 524288;

    (void)hipMemsetAsync(out, 0, (size_t)8192 * 4, stream);  // context accumulated via atomics

    k_prep<<<120, 256, 0, stream>>>(Wm, Wconv, Wloc, query, Wq,
                                    pwmhi, pwmlo, wcthi, wctlo, pwlhi, pwllo, q_ws);
    k_zq<<<BB, 256, 0, stream>>>(xcat, pwlhi, pwllo, zthi, ztlo);
    k_main<<<512, 256, 0, stream>>>(value, pwmhi, pwmlo, wcthi, wctlo, zthi, ztlo,
                                    q_ws, Wv, v_ws, sc_ws);
    k_softmax<<<BB, 256, 0, stream>>>(sc_ws, out + 8192);
    k_context<<<dim3(16, BB), 256, 0, stream>>>(out + 8192, v_ws, out);
}